// Round 9
// baseline (243.381 us; speedup 1.0000x reference)
//
#include <hip/hip_runtime.h>

// Problem constants
#define B_ 8
#define V_ 10000
#define E_ 160000
#define DIN 128
#define DOUT 128
#define M_ (B_*V_)          // 80000 rows
#define NINV (1.0f/80000.0f)
#define BN_EPS 1e-5f

#define GEMM_BLOCKS 2500    // 32 rows x 128 cols per block; wave w owns cols w*32
#define CAP 64              // per-dst bucket capacity (Poisson(16) degrees)

// Workspace layout (4-byte units). Zero region is [0, WS_ZERO_UNITS):
#define WS_CNT     0            // 10000
#define WS_SUM     10000        // 128
#define WS_SUMSQ   10128        // 128
#define WS_ZERO_UNITS 10256     // 41 KB memset
#define WS_S       10256        // 80000 -> 90256 (written unconditionally)
#define WS_SSRC    90256        // V_*CAP = 640000 -> 730256
#define WS_EAS     730256       // V_*CAP*8 = 5,120,000 -> 5,850,256 (32B aligned)
#define WS_HH      730256       // f16 pre-norm H ALIASES EAs (dead after gather)
#define WS_WPK     5850256      // 16384 units (32768 f16) -> 5,866,640 (16B aligned)
#define WS_XH      5866640      // 5,120,000 units -> 10,986,640 (16B aligned)
#define WS_AH      10986640     // 5,120,000 units -> 16,106,640 (64.4 MB total)

typedef __attribute__((ext_vector_type(2))) _Float16 half2_t;
typedef __attribute__((ext_vector_type(4))) _Float16 half4_t;
typedef __attribute__((ext_vector_type(8))) _Float16 half8_t;
typedef __attribute__((ext_vector_type(4))) float f32x4;

__device__ inline half2_t i2h(unsigned i) {
    half2_t h; __builtin_memcpy(&h, &i, 4); return h;
}
__device__ inline unsigned h2i(half2_t h) {
    unsigned i; __builtin_memcpy(&i, &h, 4); return i;
}

// ---------------------------------------------------------------------------
// 1) fused prep: X->f16 row-major (blocks 0..9999)
//              + W fragment-major f16 pack (blocks 10000..10015)
//              + edge scatter into capacity-64 dst buckets + EAs presort
//                (blocks 10016..10640).
// ---------------------------------------------------------------------------
__global__ __launch_bounds__(256) void prep_kernel(
    const float* __restrict__ X, _Float16* __restrict__ Xh,
    const float* __restrict__ Wself, const float* __restrict__ Wnode,
    _Float16* __restrict__ Wpk,
    const int* __restrict__ EI, const float* __restrict__ EA,
    int* __restrict__ cnt, int* __restrict__ ssrc, float* __restrict__ EAs)
{
    const int blk = blockIdx.x;
    const int t = threadIdx.x;
    if (blk < 10000) {
        int idx = blk * 256 + t;                 // over M_*DIN/4
        float4 v = ((const float4*)X)[idx];
        half4_t o = { (_Float16)v.x, (_Float16)v.y, (_Float16)v.z, (_Float16)v.w };
        ((half4_t*)Xh)[idx] = o;
    } else if (blk < 10016) {
        int g = (blk - 10000) * 256 + t;         // 0..4095
        int pair = g >> 6;                       // (ks,nt)
        int lane = g & 63;
        int ks = pair >> 3;
        int nt = pair & 7;
        int o = nt * 16 + (lane & 15);
        int k = ks * 32 + (lane >> 4) * 8;
        const float* wsrc = (k < 128) ? (Wself + o * 128 + k)
                                      : (Wnode + o * 128 + (k - 128));
        _Float16* dst = Wpk + ((size_t)pair * 64 + lane) * 8;
#pragma unroll
        for (int j = 0; j < 8; ++j) dst[j] = (_Float16)wsrc[j];
    } else {
        int e = (blk - 10016) * 256 + t;         // 625*256 == E_ exactly
        int src = EI[2 * e];
        int dst = EI[2 * e + 1];
        int slot = atomicAdd(&cnt[dst], 1);
        if (slot < CAP) {
            int p = dst * CAP + slot;
            ssrc[p] = src;
            float4 v0, v1;
            v0.x = EA[0 * E_ + e]; v0.y = EA[1 * E_ + e];
            v0.z = EA[2 * E_ + e]; v0.w = EA[3 * E_ + e];
            v1.x = EA[4 * E_ + e]; v1.y = EA[5 * E_ + e];
            v1.z = EA[6 * E_ + e]; v1.w = EA[7 * E_ + e];
            *(float4*)(EAs + (size_t)p * 8) = v0;
            *(float4*)(EAs + (size_t)p * 8 + 4) = v1;
        }
    }
}

// ---------------------------------------------------------------------------
// 2) gather-reduce, f16, 4 edges per load-step, batch-per-XCD swizzled.
//    One wave per (batch,row): 80000 waves of TLP.
// ---------------------------------------------------------------------------
__global__ __launch_bounds__(256) void gather_kernel(
    const _Float16* __restrict__ Xh, const float* __restrict__ EAs,
    const int* __restrict__ cnt, const int* __restrict__ ssrc,
    _Float16* __restrict__ Ah, float* __restrict__ S)
{
    const int b = blockIdx.x & 7;             // batch -> XCD
    const int dblk = blockIdx.x >> 3;         // 0..2499
    const int w = threadIdx.x >> 6;           // 4 waves/block
    const int lane = threadIdx.x & 63;
    const int q = lane >> 4;                  // which edge of the 4-pack
    const int sl = lane & 15;                 // 16B segment: halves sl*8..sl*8+7
    const int d = dblk * 4 + w;
    const int wid = b * V_ + d;
    const int deg = min(cnt[d], CAP);
    const int k0 = d * CAP;
    const _Float16* Xb = Xh + (size_t)b * V_ * DIN + sl * 8;
    half2_t a0 = (half2_t)0, a1 = (half2_t)0, a2 = (half2_t)0, a3 = (half2_t)0;
    float ea = 0.0f;
    {
        int msrc = 0;
        if (lane < deg) {
            msrc = ssrc[k0 + lane];
            ea = EAs[(size_t)(k0 + lane) * 8 + b];
        }
        int j = 0;
        for (; j + 16 <= deg; j += 16) {
#pragma unroll
            for (int u = 0; u < 4; ++u) {
                int s = __shfl(msrc, j + u * 4 + q);
                uint4 v = *(const uint4*)(Xb + (size_t)s * DIN);
                a0 += i2h(v.x); a1 += i2h(v.y); a2 += i2h(v.z); a3 += i2h(v.w);
            }
        }
        for (; j + 4 <= deg; j += 4) {
            int s = __shfl(msrc, j + q);
            uint4 v = *(const uint4*)(Xb + (size_t)s * DIN);
            a0 += i2h(v.x); a1 += i2h(v.y); a2 += i2h(v.z); a3 += i2h(v.w);
        }
        if (j < deg) {
            int s = __shfl(msrc, j + q);
            if (j + q < deg) {
                uint4 v = *(const uint4*)(Xb + (size_t)s * DIN);
                a0 += i2h(v.x); a1 += i2h(v.y); a2 += i2h(v.z); a3 += i2h(v.w);
            }
        }
    }
#pragma unroll
    for (int off = 32; off >= 16; off >>= 1) {
        a0 += i2h(__shfl_down(h2i(a0), off));
        a1 += i2h(__shfl_down(h2i(a1), off));
        a2 += i2h(__shfl_down(h2i(a2), off));
        a3 += i2h(__shfl_down(h2i(a3), off));
    }
    for (int off = 32; off; off >>= 1) ea += __shfl_down(ea, off);
    if (lane == 0) S[wid] = ea;
    if (lane < 16) {
        uint4 o;
        o.x = h2i(a0); o.y = h2i(a1); o.z = h2i(a2); o.w = h2i(a3);
        *(uint4*)(Ah + (size_t)wid * DIN + sl * 8) = o;
    }
}

// ---------------------------------------------------------------------------
// 3) MLP-tiled zero-barrier GEMM + stats. BW-latency product: 6.3 TB/s at
//    ~375ns needs ~2.4 MB of reads in flight; R8's 2500 waves x ~8 loads =
//    0.3 MB -> measured ~1 TB/s, pinned 43 us across 3 structures. Fix:
//    grid 2500 (10000 waves), each wave bursts ALL 16 A-fragments up front
//    (256B in flight/wave) and streams B from L2. Wave w owns cols w*32
//    (stats stay wave-exclusive: shfl + global atomics, no LDS, no barrier).
// ---------------------------------------------------------------------------
__global__ __launch_bounds__(256, 4) void gemm_stats_kernel(
    const _Float16* __restrict__ Xh, const _Float16* __restrict__ Ah,
    const _Float16* __restrict__ Wpk, const float* __restrict__ S,
    const float* __restrict__ bself, const float* __restrict__ wedge,
    _Float16* __restrict__ Hh, float* __restrict__ gsum,
    float* __restrict__ gsumsq)
{
    const int t = threadIdx.x;
    const int wave = t >> 6;           // col slice: nt_global = wave*2 + ntl
    const int lane = t & 63;
    const int quad = lane >> 4;
    const int ln = lane & 15;
    const int rowbase = blockIdx.x * 32;

    // A burst: this block's 32 rows x K=256 ([X | agg]) = 16 independent
    // dwordx4 loads issued before anything depends on them.
    const _Float16* Xr = Xh + (size_t)(rowbase + ln) * DIN + quad * 8;
    const _Float16* Ar = Ah + (size_t)(rowbase + ln) * DIN + quad * 8;
    half8_t afr[2][8];                 // [mt][ks]
#pragma unroll
    for (int ks = 0; ks < 4; ++ks) {
#pragma unroll
        for (int mt = 0; mt < 2; ++mt) {
            afr[mt][ks]     = *(const half8_t*)(Xr + (size_t)mt * 16 * DIN + ks * 32);
            afr[mt][4 + ks] = *(const half8_t*)(Ar + (size_t)mt * 16 * DIN + ks * 32);
        }
    }

    f32x4 acc[2][2];
#pragma unroll
    for (int mt = 0; mt < 2; ++mt)
#pragma unroll
        for (int ntl = 0; ntl < 2; ++ntl) acc[mt][ntl] = (f32x4){0.f,0.f,0.f,0.f};

    // B streamed per K-step from L2 (compiler hoists ahead within VGPR budget)
#pragma unroll
    for (int ks = 0; ks < 8; ++ks) {
        half8_t b0 = *(const half8_t*)(
            Wpk + ((size_t)(ks * 8 + wave * 2 + 0) * 64 + lane) * 8);
        half8_t b1 = *(const half8_t*)(
            Wpk + ((size_t)(ks * 8 + wave * 2 + 1) * 64 + lane) * 8);
        acc[0][0] = __builtin_amdgcn_mfma_f32_16x16x32_f16(afr[0][ks], b0, acc[0][0], 0, 0, 0);
        acc[0][1] = __builtin_amdgcn_mfma_f32_16x16x32_f16(afr[0][ks], b1, acc[0][1], 0, 0, 0);
        acc[1][0] = __builtin_amdgcn_mfma_f32_16x16x32_f16(afr[1][ks], b0, acc[1][0], 0, 0, 0);
        acc[1][1] = __builtin_amdgcn_mfma_f32_16x16x32_f16(afr[1][ks], b1, acc[1][1], 0, 0, 0);
    }

    // epilogue: bias + S*w_edge, f16 Hh store, per-channel stats (shfl-only)
    float bs[2], we[2];
#pragma unroll
    for (int ntl = 0; ntl < 2; ++ntl) {
        int c = wave * 32 + ntl * 16 + ln;
        bs[ntl] = bself[c];
        we[ntl] = wedge[c];
    }
    float psum[2] = {0.f, 0.f}, psq[2] = {0.f, 0.f};

#pragma unroll
    for (int mt = 0; mt < 2; ++mt) {
        const int rb = rowbase + mt * 16 + quad * 4;
        float sv[4];
#pragma unroll
        for (int r = 0; r < 4; ++r) sv[r] = S[rb + r];
#pragma unroll
        for (int r = 0; r < 4; ++r) {
            _Float16* Hr = Hh + (size_t)(rb + r) * DOUT + wave * 32 + ln;
#pragma unroll
            for (int ntl = 0; ntl < 2; ++ntl) {
                float h = acc[mt][ntl][r] + bs[ntl] + sv[r] * we[ntl];
                Hr[ntl * 16] = (_Float16)h;
                psum[ntl] += h;
                psq[ntl] += h * h;
            }
        }
    }
    // reduce across the 4 quads (rows) -> lanes 0..15 hold channel totals
#pragma unroll
    for (int ntl = 0; ntl < 2; ++ntl) {
        psum[ntl] += __shfl_down(psum[ntl], 32);
        psum[ntl] += __shfl_down(psum[ntl], 16);
        psq[ntl]  += __shfl_down(psq[ntl], 32);
        psq[ntl]  += __shfl_down(psq[ntl], 16);
    }
    if (lane < 16) {
#pragma unroll
        for (int ntl = 0; ntl < 2; ++ntl) {
            int c = wave * 32 + ntl * 16 + lane;
            atomicAdd(&gsum[c], psum[ntl]);
            atomicAdd(&gsumsq[c], psq[ntl]);
        }
    }
}

// ---------------------------------------------------------------------------
// 4) streaming normalize + ReLU: read f16 Hh (20.5 MB), write fp32 H (41 MB).
// ---------------------------------------------------------------------------
__global__ __launch_bounds__(256) void norm_relu_kernel(
    const _Float16* __restrict__ Hh, float* __restrict__ H,
    const float* __restrict__ gsum, const float* __restrict__ gsumsq,
    const float* __restrict__ gamma, const float* __restrict__ beta)
{
    const int total = M_ * DOUT / 8;           // 1.28M groups of 8 f16
    for (int idx = blockIdx.x * 256 + threadIdx.x; idx < total;
         idx += gridDim.x * 256) {
        int o8 = (idx & 15) * 8;               // channel base (0..120)
        float4 s0 = *(const float4*)(gsum + o8);
        float4 s1 = *(const float4*)(gsum + o8 + 4);
        float4 q0 = *(const float4*)(gsumsq + o8);
        float4 q1 = *(const float4*)(gsumsq + o8 + 4);
        float4 g0 = *(const float4*)(gamma + o8);
        float4 g1 = *(const float4*)(gamma + o8 + 4);
        float4 b0 = *(const float4*)(beta + o8);
        float4 b1 = *(const float4*)(beta + o8 + 4);
        float sc[8], sh[8];
        float svv[8] = {s0.x, s0.y, s0.z, s0.w, s1.x, s1.y, s1.z, s1.w};
        float qv[8] = {q0.x, q0.y, q0.z, q0.w, q1.x, q1.y, q1.z, q1.w};
        float gv[8] = {g0.x, g0.y, g0.z, g0.w, g1.x, g1.y, g1.z, g1.w};
        float bv[8] = {b0.x, b0.y, b0.z, b0.w, b1.x, b1.y, b1.z, b1.w};
#pragma unroll
        for (int j = 0; j < 8; ++j) {
            float mean = svv[j] * NINV;
            float rstd = rsqrtf(qv[j] * NINV - mean * mean + BN_EPS);
            sc[j] = gv[j] * rstd;
            sh[j] = bv[j] - mean * sc[j];
        }
        half8_t hv = ((const half8_t*)Hh)[idx];
        float4 o0, o1;
        o0.x = fmaxf((float)hv[0] * sc[0] + sh[0], 0.0f);
        o0.y = fmaxf((float)hv[1] * sc[1] + sh[1], 0.0f);
        o0.z = fmaxf((float)hv[2] * sc[2] + sh[2], 0.0f);
        o0.w = fmaxf((float)hv[3] * sc[3] + sh[3], 0.0f);
        o1.x = fmaxf((float)hv[4] * sc[4] + sh[4], 0.0f);
        o1.y = fmaxf((float)hv[5] * sc[5] + sh[5], 0.0f);
        o1.z = fmaxf((float)hv[6] * sc[6] + sh[6], 0.0f);
        o1.w = fmaxf((float)hv[7] * sc[7] + sh[7], 0.0f);
        ((float4*)H)[idx * 2]     = o0;
        ((float4*)H)[idx * 2 + 1] = o1;
    }
}

// ---------------------------------------------------------------------------
extern "C" void kernel_launch(void* const* d_in, const int* in_sizes, int n_in,
                              void* d_out, int out_size, void* d_ws, size_t ws_size,
                              hipStream_t stream)
{
    const float* X      = (const float*)d_in[0];
    const float* EA     = (const float*)d_in[1];
    const float* Wnode  = (const float*)d_in[2];
    const float* Wedge  = (const float*)d_in[3];
    const float* Wself  = (const float*)d_in[4];
    const float* bself  = (const float*)d_in[5];
    const float* gamma  = (const float*)d_in[6];
    const float* beta   = (const float*)d_in[7];
    const int*   EI     = (const int*)d_in[8];

    int*   wsI    = (int*)d_ws;
    float* wsF    = (float*)d_ws;
    int*   cnt    = wsI + WS_CNT;
    float* gsum   = wsF + WS_SUM;
    float* gsumsq = wsF + WS_SUMSQ;
    float* S      = wsF + WS_S;
    int*   ssrc   = wsI + WS_SSRC;
    float* EAs    = wsF + WS_EAS;
    _Float16* Hh  = (_Float16*)(wsI + WS_HH);   // aliases EAs (dead after gather)
    _Float16* Wpk = (_Float16*)(wsI + WS_WPK);
    _Float16* Xh  = (_Float16*)(wsI + WS_XH);
    _Float16* Ah  = (_Float16*)(wsI + WS_AH);
    float* H      = (float*)d_out;

    // zero cnt + gsum + gsumsq (41 KB)
    hipMemsetAsync(d_ws, 0, (size_t)WS_ZERO_UNITS * 4, stream);

    // fused prep: xcvt (10000 blocks) + W pack (16) + edge scatter (625)
    prep_kernel<<<10641, 256, 0, stream>>>(X, Xh, Wself, Wnode, Wpk, EI, EA,
                                           cnt, ssrc, EAs);

    // gather-reduce -> Ah, S  (batch-per-XCD swizzle, 4 edges/load-step)
    gather_kernel<<<M_ / 4, 256, 0, stream>>>(Xh, EAs, cnt, ssrc, Ah, S);

    // MLP-tiled zero-barrier GEMM -> f16 Hh + gsum/gsumsq via atomics
    gemm_stats_kernel<<<GEMM_BLOCKS, 256, 0, stream>>>(Xh, Ah, Wpk, S, bself,
                                                       Wedge, Hh, gsum, gsumsq);

    // streaming normalize + ReLU: f16 in, fp32 out
    norm_relu_kernel<<<2048, 256, 0, stream>>>(Hh, H, gsum, gsumsq, gamma, beta);
}

// Round 10
// 233.947 us; speedup vs baseline: 1.0403x; 1.0403x over previous
//
#include <hip/hip_runtime.h>

// Problem constants
#define B_ 8
#define V_ 10000
#define E_ 160000
#define DIN 128
#define DOUT 128
#define M_ (B_*V_)          // 80000 rows
#define NINV (1.0f/80000.0f)
#define BN_EPS 1e-5f

#define GEMM_BLOCKS 2500    // 32 rows x 128 cols per block; wave w owns cols w*32
#define CAP 64              // per-dst bucket capacity (Poisson(16) degrees)

// Workspace layout (4-byte units). Zero region is [0, WS_ZERO_UNITS):
#define WS_CNT     0            // 10000
#define WS_SUM     10000        // 128
#define WS_SUMSQ   10128        // 128
#define WS_ZERO_UNITS 10256     // 41 KB memset
#define WS_S       10256        // 80000 -> 90256 (written unconditionally)
#define WS_SSRC    90256        // V_*CAP = 640000 -> 730256
#define WS_EAS     730256       // V_*CAP*8 = 5,120,000 -> 5,850,256 (32B aligned)
#define WS_HH      730256       // f16 pre-norm H ALIASES EAs (dead after gather)
#define WS_WPK     5850256      // 16384 units (32768 f16) -> 5,866,640 (16B aligned)
#define WS_XH      5866640      // 5,120,000 units -> 10,986,640 (16B aligned)
#define WS_AH      10986640     // 5,120,000 units -> 16,106,640 (64.4 MB total)

typedef __attribute__((ext_vector_type(2))) _Float16 half2_t;
typedef __attribute__((ext_vector_type(4))) _Float16 half4_t;
typedef __attribute__((ext_vector_type(8))) _Float16 half8_t;
typedef __attribute__((ext_vector_type(4))) float f32x4;

__device__ inline half2_t i2h(unsigned i) {
    half2_t h; __builtin_memcpy(&h, &i, 4); return h;
}
__device__ inline unsigned h2i(half2_t h) {
    unsigned i; __builtin_memcpy(&i, &h, 4); return i;
}

// ---------------------------------------------------------------------------
// 1) fused prep: X->f16 row-major (blocks 0..9999)
//              + W fragment-major f16 pack (blocks 10000..10015)
//              + edge scatter into capacity-64 dst buckets + EAs presort
//                (blocks 10016..10640).
// ---------------------------------------------------------------------------
__global__ __launch_bounds__(256) void prep_kernel(
    const float* __restrict__ X, _Float16* __restrict__ Xh,
    const float* __restrict__ Wself, const float* __restrict__ Wnode,
    _Float16* __restrict__ Wpk,
    const int* __restrict__ EI, const float* __restrict__ EA,
    int* __restrict__ cnt, int* __restrict__ ssrc, float* __restrict__ EAs)
{
    const int blk = blockIdx.x;
    const int t = threadIdx.x;
    if (blk < 10000) {
        int idx = blk * 256 + t;                 // over M_*DIN/4
        float4 v = ((const float4*)X)[idx];
        half4_t o = { (_Float16)v.x, (_Float16)v.y, (_Float16)v.z, (_Float16)v.w };
        ((half4_t*)Xh)[idx] = o;
    } else if (blk < 10016) {
        int g = (blk - 10000) * 256 + t;         // 0..4095
        int pair = g >> 6;                       // (ks,nt)
        int lane = g & 63;
        int ks = pair >> 3;
        int nt = pair & 7;
        int o = nt * 16 + (lane & 15);
        int k = ks * 32 + (lane >> 4) * 8;
        const float* wsrc = (k < 128) ? (Wself + o * 128 + k)
                                      : (Wnode + o * 128 + (k - 128));
        _Float16* dst = Wpk + ((size_t)pair * 64 + lane) * 8;
#pragma unroll
        for (int j = 0; j < 8; ++j) dst[j] = (_Float16)wsrc[j];
    } else {
        int e = (blk - 10016) * 256 + t;         // 625*256 == E_ exactly
        int src = EI[2 * e];
        int dst = EI[2 * e + 1];
        int slot = atomicAdd(&cnt[dst], 1);
        if (slot < CAP) {
            int p = dst * CAP + slot;
            ssrc[p] = src;
            float4 v0, v1;
            v0.x = EA[0 * E_ + e]; v0.y = EA[1 * E_ + e];
            v0.z = EA[2 * E_ + e]; v0.w = EA[3 * E_ + e];
            v1.x = EA[4 * E_ + e]; v1.y = EA[5 * E_ + e];
            v1.z = EA[6 * E_ + e]; v1.w = EA[7 * E_ + e];
            *(float4*)(EAs + (size_t)p * 8) = v0;
            *(float4*)(EAs + (size_t)p * 8 + 4) = v1;
        }
    }
}

// ---------------------------------------------------------------------------
// 2) gather-reduce, f16, 4 edges per load-step, batch-per-XCD swizzled.
//    One wave per (batch,row): 80000 waves of TLP.
// ---------------------------------------------------------------------------
__global__ __launch_bounds__(256) void gather_kernel(
    const _Float16* __restrict__ Xh, const float* __restrict__ EAs,
    const int* __restrict__ cnt, const int* __restrict__ ssrc,
    _Float16* __restrict__ Ah, float* __restrict__ S)
{
    const int b = blockIdx.x & 7;             // batch -> XCD
    const int dblk = blockIdx.x >> 3;         // 0..2499
    const int w = threadIdx.x >> 6;           // 4 waves/block
    const int lane = threadIdx.x & 63;
    const int q = lane >> 4;                  // which edge of the 4-pack
    const int sl = lane & 15;                 // 16B segment: halves sl*8..sl*8+7
    const int d = dblk * 4 + w;
    const int wid = b * V_ + d;
    const int deg = min(cnt[d], CAP);
    const int k0 = d * CAP;
    const _Float16* Xb = Xh + (size_t)b * V_ * DIN + sl * 8;
    half2_t a0 = (half2_t)0, a1 = (half2_t)0, a2 = (half2_t)0, a3 = (half2_t)0;
    float ea = 0.0f;
    {
        int msrc = 0;
        if (lane < deg) {
            msrc = ssrc[k0 + lane];
            ea = EAs[(size_t)(k0 + lane) * 8 + b];
        }
        int j = 0;
        for (; j + 16 <= deg; j += 16) {
#pragma unroll
            for (int u = 0; u < 4; ++u) {
                int s = __shfl(msrc, j + u * 4 + q);
                uint4 v = *(const uint4*)(Xb + (size_t)s * DIN);
                a0 += i2h(v.x); a1 += i2h(v.y); a2 += i2h(v.z); a3 += i2h(v.w);
            }
        }
        for (; j + 4 <= deg; j += 4) {
            int s = __shfl(msrc, j + q);
            uint4 v = *(const uint4*)(Xb + (size_t)s * DIN);
            a0 += i2h(v.x); a1 += i2h(v.y); a2 += i2h(v.z); a3 += i2h(v.w);
        }
        if (j < deg) {
            int s = __shfl(msrc, j + q);
            if (j + q < deg) {
                uint4 v = *(const uint4*)(Xb + (size_t)s * DIN);
                a0 += i2h(v.x); a1 += i2h(v.y); a2 += i2h(v.z); a3 += i2h(v.w);
            }
        }
    }
#pragma unroll
    for (int off = 32; off >= 16; off >>= 1) {
        a0 += i2h(__shfl_down(h2i(a0), off));
        a1 += i2h(__shfl_down(h2i(a1), off));
        a2 += i2h(__shfl_down(h2i(a2), off));
        a3 += i2h(__shfl_down(h2i(a3), off));
    }
    for (int off = 32; off; off >>= 1) ea += __shfl_down(ea, off);
    if (lane == 0) S[wid] = ea;
    if (lane < 16) {
        uint4 o;
        o.x = h2i(a0); o.y = h2i(a1); o.z = h2i(a2); o.w = h2i(a3);
        *(uint4*)(Ah + (size_t)wid * DIN + sl * 8) = o;
    }
}

// ---------------------------------------------------------------------------
// 3) GEMM + stats, large-grid + A-in-LDS-via-DMA. R9 failed because the
//    register A-"burst" was de-scheduled by the allocator (VGPR_Count=28 ->
//    ~2 loads in flight). Fix: stage A through global_load_lds, whose
//    in-flight data lives in the DMA queue, not VGPRs. Per block: 32 rows x
//    [Xh|Ah] = 16 KB A-tile, 16 chunks issued instantly; all 4 waves reuse
//    the same tile (A-reuse x4). B streams L2->reg per K-step. The 512B row
//    stride is a 16-way bank conflict if linear -> pre-swizzled global
//    SOURCE (rule #21: scol = col16 ^ (row&7), stays within its half) +
//    same XOR on the ds_read address = every bank exactly 8 words/read.
//    One barrier; stats wave-exclusive (shfl + global atomics); no W LDS.
// ---------------------------------------------------------------------------
__global__ __launch_bounds__(256, 4) void gemm_stats_kernel(
    const _Float16* __restrict__ Xh, const _Float16* __restrict__ Ah,
    const _Float16* __restrict__ Wpk, const float* __restrict__ S,
    const float* __restrict__ bself, const float* __restrict__ wedge,
    _Float16* __restrict__ Hh, float* __restrict__ gsum,
    float* __restrict__ gsumsq)
{
    __shared__ _Float16 aLds[8192];    // 16 KB: 32 rows x 512 B, XOR-swizzled
    const int t = threadIdx.x;
    const int wave = t >> 6;           // col slice: nt_global = wave*2 + ntl
    const int lane = t & 63;
    const int quad = lane >> 4;
    const int ln = lane & 15;
    const int rowbase = blockIdx.x * 32;

    // stage A-tile: 16 x 1KB chunks, 4 per wave; per-lane PRE-SWIZZLED global
    // source, linear LDS dest (base + lane*16). Chunk c covers rows 2c,2c+1.
#pragma unroll
    for (int i = 0; i < 4; ++i) {
        int c = wave * 4 + i;
        int row = 2 * c + (lane >> 5);
        int col16 = lane & 31;               // 16B unit within the 512B row
        int scol = col16 ^ (row & 7);        // inverse swizzle on the SOURCE
        int m = rowbase + row;
        const _Float16* src = (scol < 16)
            ? Xh + (size_t)m * DIN + scol * 8
            : Ah + (size_t)m * DIN + (scol - 16) * 8;
        __builtin_amdgcn_global_load_lds(
            (const __attribute__((address_space(1))) void*)src,
            (__attribute__((address_space(3))) void*)
                ((char*)aLds + (size_t)c * 1024),
            16, 0, 0);
    }

    f32x4 acc[2][2];
#pragma unroll
    for (int mt = 0; mt < 2; ++mt)
#pragma unroll
        for (int ntl = 0; ntl < 2; ++ntl) acc[mt][ntl] = (f32x4){0.f,0.f,0.f,0.f};

    __syncthreads();   // drains the 16 DMA chunks; only barrier in the kernel

#pragma unroll
    for (int ks = 0; ks < 8; ++ks) {
        // B fragments for this wave's two col-tiles (L2-resident, 16B each)
        half8_t b0 = *(const half8_t*)(
            Wpk + ((size_t)(ks * 8 + wave * 2 + 0) * 64 + lane) * 8);
        half8_t b1 = *(const half8_t*)(
            Wpk + ((size_t)(ks * 8 + wave * 2 + 1) * 64 + lane) * 8);
#pragma unroll
        for (int mt = 0; mt < 2; ++mt) {
            int row = mt * 16 + ln;
            int u = (ks * 4 + quad) ^ (row & 7);       // swizzled 16B unit
            half8_t af = *(const half8_t*)(
                (const char*)aLds + (size_t)row * 512 + (size_t)u * 16);
            acc[mt][0] = __builtin_amdgcn_mfma_f32_16x16x32_f16(af, b0, acc[mt][0], 0, 0, 0);
            acc[mt][1] = __builtin_amdgcn_mfma_f32_16x16x32_f16(af, b1, acc[mt][1], 0, 0, 0);
        }
    }

    // epilogue: bias + S*w_edge, f16 Hh store, per-channel stats (shfl-only)
    float bs[2], we[2];
#pragma unroll
    for (int ntl = 0; ntl < 2; ++ntl) {
        int c = wave * 32 + ntl * 16 + ln;
        bs[ntl] = bself[c];
        we[ntl] = wedge[c];
    }
    float psum[2] = {0.f, 0.f}, psq[2] = {0.f, 0.f};

#pragma unroll
    for (int mt = 0; mt < 2; ++mt) {
        const int rb = rowbase + mt * 16 + quad * 4;
        float sv[4];
#pragma unroll
        for (int r = 0; r < 4; ++r) sv[r] = S[rb + r];
#pragma unroll
        for (int r = 0; r < 4; ++r) {
            _Float16* Hr = Hh + (size_t)(rb + r) * DOUT + wave * 32 + ln;
#pragma unroll
            for (int ntl = 0; ntl < 2; ++ntl) {
                float h = acc[mt][ntl][r] + bs[ntl] + sv[r] * we[ntl];
                Hr[ntl * 16] = (_Float16)h;
                psum[ntl] += h;
                psq[ntl] += h * h;
            }
        }
    }
    // reduce across the 4 quads (rows) -> lanes 0..15 hold channel totals
#pragma unroll
    for (int ntl = 0; ntl < 2; ++ntl) {
        psum[ntl] += __shfl_down(psum[ntl], 32);
        psum[ntl] += __shfl_down(psum[ntl], 16);
        psq[ntl]  += __shfl_down(psq[ntl], 32);
        psq[ntl]  += __shfl_down(psq[ntl], 16);
    }
    if (lane < 16) {
#pragma unroll
        for (int ntl = 0; ntl < 2; ++ntl) {
            int c = wave * 32 + ntl * 16 + lane;
            atomicAdd(&gsum[c], psum[ntl]);
            atomicAdd(&gsumsq[c], psq[ntl]);
        }
    }
}

// ---------------------------------------------------------------------------
// 4) streaming normalize + ReLU: read f16 Hh (20.5 MB), write fp32 H (41 MB).
// ---------------------------------------------------------------------------
__global__ __launch_bounds__(256) void norm_relu_kernel(
    const _Float16* __restrict__ Hh, float* __restrict__ H,
    const float* __restrict__ gsum, const float* __restrict__ gsumsq,
    const float* __restrict__ gamma, const float* __restrict__ beta)
{
    const int total = M_ * DOUT / 8;           // 1.28M groups of 8 f16
    for (int idx = blockIdx.x * 256 + threadIdx.x; idx < total;
         idx += gridDim.x * 256) {
        int o8 = (idx & 15) * 8;               // channel base (0..120)
        float4 s0 = *(const float4*)(gsum + o8);
        float4 s1 = *(const float4*)(gsum + o8 + 4);
        float4 q0 = *(const float4*)(gsumsq + o8);
        float4 q1 = *(const float4*)(gsumsq + o8 + 4);
        float4 g0 = *(const float4*)(gamma + o8);
        float4 g1 = *(const float4*)(gamma + o8 + 4);
        float4 b0 = *(const float4*)(beta + o8);
        float4 b1 = *(const float4*)(beta + o8 + 4);
        float sc[8], sh[8];
        float svv[8] = {s0.x, s0.y, s0.z, s0.w, s1.x, s1.y, s1.z, s1.w};
        float qv[8] = {q0.x, q0.y, q0.z, q0.w, q1.x, q1.y, q1.z, q1.w};
        float gv[8] = {g0.x, g0.y, g0.z, g0.w, g1.x, g1.y, g1.z, g1.w};
        float bv[8] = {b0.x, b0.y, b0.z, b0.w, b1.x, b1.y, b1.z, b1.w};
#pragma unroll
        for (int j = 0; j < 8; ++j) {
            float mean = svv[j] * NINV;
            float rstd = rsqrtf(qv[j] * NINV - mean * mean + BN_EPS);
            sc[j] = gv[j] * rstd;
            sh[j] = bv[j] - mean * sc[j];
        }
        half8_t hv = ((const half8_t*)Hh)[idx];
        float4 o0, o1;
        o0.x = fmaxf((float)hv[0] * sc[0] + sh[0], 0.0f);
        o0.y = fmaxf((float)hv[1] * sc[1] + sh[1], 0.0f);
        o0.z = fmaxf((float)hv[2] * sc[2] + sh[2], 0.0f);
        o0.w = fmaxf((float)hv[3] * sc[3] + sh[3], 0.0f);
        o1.x = fmaxf((float)hv[4] * sc[4] + sh[4], 0.0f);
        o1.y = fmaxf((float)hv[5] * sc[5] + sh[5], 0.0f);
        o1.z = fmaxf((float)hv[6] * sc[6] + sh[6], 0.0f);
        o1.w = fmaxf((float)hv[7] * sc[7] + sh[7], 0.0f);
        ((float4*)H)[idx * 2]     = o0;
        ((float4*)H)[idx * 2 + 1] = o1;
    }
}

// ---------------------------------------------------------------------------
extern "C" void kernel_launch(void* const* d_in, const int* in_sizes, int n_in,
                              void* d_out, int out_size, void* d_ws, size_t ws_size,
                              hipStream_t stream)
{
    const float* X      = (const float*)d_in[0];
    const float* EA     = (const float*)d_in[1];
    const float* Wnode  = (const float*)d_in[2];
    const float* Wedge  = (const float*)d_in[3];
    const float* Wself  = (const float*)d_in[4];
    const float* bself  = (const float*)d_in[5];
    const float* gamma  = (const float*)d_in[6];
    const float* beta   = (const float*)d_in[7];
    const int*   EI     = (const int*)d_in[8];

    int*   wsI    = (int*)d_ws;
    float* wsF    = (float*)d_ws;
    int*   cnt    = wsI + WS_CNT;
    float* gsum   = wsF + WS_SUM;
    float* gsumsq = wsF + WS_SUMSQ;
    float* S      = wsF + WS_S;
    int*   ssrc   = wsI + WS_SSRC;
    float* EAs    = wsF + WS_EAS;
    _Float16* Hh  = (_Float16*)(wsI + WS_HH);   // aliases EAs (dead after gather)
    _Float16* Wpk = (_Float16*)(wsI + WS_WPK);
    _Float16* Xh  = (_Float16*)(wsI + WS_XH);
    _Float16* Ah  = (_Float16*)(wsI + WS_AH);
    float* H      = (float*)d_out;

    // zero cnt + gsum + gsumsq (41 KB)
    hipMemsetAsync(d_ws, 0, (size_t)WS_ZERO_UNITS * 4, stream);

    // fused prep: xcvt (10000 blocks) + W pack (16) + edge scatter (625)
    prep_kernel<<<10641, 256, 0, stream>>>(X, Xh, Wself, Wnode, Wpk, EI, EA,
                                           cnt, ssrc, EAs);

    // gather-reduce -> Ah, S  (batch-per-XCD swizzle, 4 edges/load-step)
    gather_kernel<<<M_ / 4, 256, 0, stream>>>(Xh, EAs, cnt, ssrc, Ah, S);

    // large-grid GEMM, A staged via LDS-DMA -> f16 Hh + gsum/gsumsq
    gemm_stats_kernel<<<GEMM_BLOCKS, 256, 0, stream>>>(Xh, Ah, Wpk, S, bself,
                                                       Wedge, Hh, gsum, gsumsq);

    // streaming normalize + ReLU: f16 in, fp32 out
    norm_relu_kernel<<<2048, 256, 0, stream>>>(Hh, H, gsum, gsumsq, gamma, beta);
}

// Round 11
// 201.696 us; speedup vs baseline: 1.2067x; 1.1599x over previous
//
#include <hip/hip_runtime.h>

// Problem constants
#define B_ 8
#define V_ 10000
#define E_ 160000
#define DIN 128
#define DOUT 128
#define M_ (B_*V_)          // 80000 rows
#define NINV (1.0f/80000.0f)
#define BN_EPS 1e-5f

#define GEMM_BLOCKS 2500    // 64 rows x 64 cols per block (rblk = bid>>1, nb = bid&1)
#define CAP 64              // per-dst bucket capacity (Poisson(16) degrees)

// Workspace layout (4-byte units). Zero region is [0, WS_ZERO_UNITS):
#define WS_CNT     0            // 10000
#define WS_SUM     10000        // 128
#define WS_SUMSQ   10128        // 128
#define WS_ZERO_UNITS 10256     // 41 KB memset
#define WS_S       10256        // 80000 -> 90256 (written unconditionally)
#define WS_SSRC    90256        // V_*CAP = 640000 -> 730256
#define WS_EAS     730256       // V_*CAP*8 = 5,120,000 -> 5,850,256 (32B aligned)
#define WS_HH      730256       // f16 pre-norm H ALIASES EAs (dead after gather)
#define WS_WPK     5850256      // 16384 units (32768 f16) -> 5,866,640 (16B aligned)
#define WS_XH      5866640      // 5,120,000 units -> 10,986,640 (16B aligned)
#define WS_AH      10986640     // 5,120,000 units -> 16,106,640 (64.4 MB total)

typedef __attribute__((ext_vector_type(2))) _Float16 half2_t;
typedef __attribute__((ext_vector_type(4))) _Float16 half4_t;
typedef __attribute__((ext_vector_type(8))) _Float16 half8_t;
typedef __attribute__((ext_vector_type(4))) float f32x4;

__device__ inline half2_t i2h(unsigned i) {
    half2_t h; __builtin_memcpy(&h, &i, 4); return h;
}
__device__ inline unsigned h2i(half2_t h) {
    unsigned i; __builtin_memcpy(&i, &h, 4); return i;
}

// ---------------------------------------------------------------------------
// 1) fused prep: X->f16 row-major (blocks 0..9999)
//              + W fragment-major f16 pack (blocks 10000..10015)
//              + edge scatter into capacity-64 dst buckets + EAs presort
//                (blocks 10016..10640).
// ---------------------------------------------------------------------------
__global__ __launch_bounds__(256) void prep_kernel(
    const float* __restrict__ X, _Float16* __restrict__ Xh,
    const float* __restrict__ Wself, const float* __restrict__ Wnode,
    _Float16* __restrict__ Wpk,
    const int* __restrict__ EI, const float* __restrict__ EA,
    int* __restrict__ cnt, int* __restrict__ ssrc, float* __restrict__ EAs)
{
    const int blk = blockIdx.x;
    const int t = threadIdx.x;
    if (blk < 10000) {
        int idx = blk * 256 + t;                 // over M_*DIN/4
        float4 v = ((const float4*)X)[idx];
        half4_t o = { (_Float16)v.x, (_Float16)v.y, (_Float16)v.z, (_Float16)v.w };
        ((half4_t*)Xh)[idx] = o;
    } else if (blk < 10016) {
        int g = (blk - 10000) * 256 + t;         // 0..4095
        int pair = g >> 6;                       // (ks,nt)
        int lane = g & 63;
        int ks = pair >> 3;
        int nt = pair & 7;
        int o = nt * 16 + (lane & 15);
        int k = ks * 32 + (lane >> 4) * 8;
        const float* wsrc = (k < 128) ? (Wself + o * 128 + k)
                                      : (Wnode + o * 128 + (k - 128));
        _Float16* dst = Wpk + ((size_t)pair * 64 + lane) * 8;
#pragma unroll
        for (int j = 0; j < 8; ++j) dst[j] = (_Float16)wsrc[j];
    } else {
        int e = (blk - 10016) * 256 + t;         // 625*256 == E_ exactly
        int src = EI[2 * e];
        int dst = EI[2 * e + 1];
        int slot = atomicAdd(&cnt[dst], 1);
        if (slot < CAP) {
            int p = dst * CAP + slot;
            ssrc[p] = src;
            float4 v0, v1;
            v0.x = EA[0 * E_ + e]; v0.y = EA[1 * E_ + e];
            v0.z = EA[2 * E_ + e]; v0.w = EA[3 * E_ + e];
            v1.x = EA[4 * E_ + e]; v1.y = EA[5 * E_ + e];
            v1.z = EA[6 * E_ + e]; v1.w = EA[7 * E_ + e];
            *(float4*)(EAs + (size_t)p * 8) = v0;
            *(float4*)(EAs + (size_t)p * 8 + 4) = v1;
        }
    }
}

// ---------------------------------------------------------------------------
// 2) gather-reduce, f16, 4 edges per load-step, batch-per-XCD swizzled.
//    One wave per (batch,row): 80000 waves of TLP.
// ---------------------------------------------------------------------------
__global__ __launch_bounds__(256) void gather_kernel(
    const _Float16* __restrict__ Xh, const float* __restrict__ EAs,
    const int* __restrict__ cnt, const int* __restrict__ ssrc,
    _Float16* __restrict__ Ah, float* __restrict__ S)
{
    const int b = blockIdx.x & 7;             // batch -> XCD
    const int dblk = blockIdx.x >> 3;         // 0..2499
    const int w = threadIdx.x >> 6;           // 4 waves/block
    const int lane = threadIdx.x & 63;
    const int q = lane >> 4;                  // which edge of the 4-pack
    const int sl = lane & 15;                 // 16B segment: halves sl*8..sl*8+7
    const int d = dblk * 4 + w;
    const int wid = b * V_ + d;
    const int deg = min(cnt[d], CAP);
    const int k0 = d * CAP;
    const _Float16* Xb = Xh + (size_t)b * V_ * DIN + sl * 8;
    half2_t a0 = (half2_t)0, a1 = (half2_t)0, a2 = (half2_t)0, a3 = (half2_t)0;
    float ea = 0.0f;
    {
        int msrc = 0;
        if (lane < deg) {
            msrc = ssrc[k0 + lane];
            ea = EAs[(size_t)(k0 + lane) * 8 + b];
        }
        int j = 0;
        for (; j + 16 <= deg; j += 16) {
#pragma unroll
            for (int u = 0; u < 4; ++u) {
                int s = __shfl(msrc, j + u * 4 + q);
                uint4 v = *(const uint4*)(Xb + (size_t)s * DIN);
                a0 += i2h(v.x); a1 += i2h(v.y); a2 += i2h(v.z); a3 += i2h(v.w);
            }
        }
        for (; j + 4 <= deg; j += 4) {
            int s = __shfl(msrc, j + q);
            uint4 v = *(const uint4*)(Xb + (size_t)s * DIN);
            a0 += i2h(v.x); a1 += i2h(v.y); a2 += i2h(v.z); a3 += i2h(v.w);
        }
        if (j < deg) {
            int s = __shfl(msrc, j + q);
            if (j + q < deg) {
                uint4 v = *(const uint4*)(Xb + (size_t)s * DIN);
                a0 += i2h(v.x); a1 += i2h(v.y); a2 += i2h(v.z); a3 += i2h(v.w);
            }
        }
    }
#pragma unroll
    for (int off = 32; off >= 16; off >>= 1) {
        a0 += i2h(__shfl_down(h2i(a0), off));
        a1 += i2h(__shfl_down(h2i(a1), off));
        a2 += i2h(__shfl_down(h2i(a2), off));
        a3 += i2h(__shfl_down(h2i(a3), off));
    }
    for (int off = 32; off; off >>= 1) ea += __shfl_down(ea, off);
    if (lane == 0) S[wid] = ea;
    if (lane < 16) {
        uint4 o;
        o.x = h2i(a0); o.y = h2i(a1); o.z = h2i(a2); o.w = h2i(a3);
        *(uint4*)(Ah + (size_t)wid * DIN + sl * 8) = o;
    }
}

// ---------------------------------------------------------------------------
// 3) GEMM + stats: BOTH operands DMA-staged. R9/R10 proved any VGPR-loaded
//    operand stream gets compiler-serialized (VGPR 28 -> ~2 loads in flight
//    -> ~0.6-1 TB/s); R5's pin was its 16 register A-loads/wave. Here each
//    64x64 block stages its A-tile (32 KB, pre-swizzled source per rule #21)
//    AND its W-slice (32 KB) via global_load_lds w16: 16 DMA/wave = 16 KB
//    in flight per wave, 8 waves/CU -> ~128 KB/CU queued -> BW-bound.
//    LDS = exactly 64 KB -> 2 blocks/CU, so next block's staging overlaps
//    this block's compute. Wave w owns cols [nb*64 + w*16 ..): stats are
//    wave-exclusive (shfl + global atomics), one barrier total.
// ---------------------------------------------------------------------------
__global__ __launch_bounds__(256, 2) void gemm_stats_kernel(
    const _Float16* __restrict__ Xh, const _Float16* __restrict__ Ah,
    const _Float16* __restrict__ Wpk, const float* __restrict__ S,
    const float* __restrict__ bself, const float* __restrict__ wedge,
    _Float16* __restrict__ Hh, float* __restrict__ gsum,
    float* __restrict__ gsumsq)
{
    __shared__ _Float16 wlds[16384];   // 32 KB: this block's W slice (8ks x 4nt)
    __shared__ _Float16 aLds[16384];   // 32 KB: 64 rows x 512 B, XOR-swizzled
    const int t = threadIdx.x;
    const int wave = t >> 6;           // owns col tile nt_global = nb*4 + wave
    const int lane = t & 63;
    const int quad = lane >> 4;
    const int ln = lane & 15;
    const int rblk = blockIdx.x >> 1;  // row block 0..1249 (64 rows)
    const int nb   = blockIdx.x & 1;   // col half 0/1
    const int rowbase = rblk * 64;

    // stage W slice: chunk c = ks*4 + wv; wave stages its own 8 (wv = wave)
#pragma unroll
    for (int i = 0; i < 8; ++i) {
        int c = i * 4 + wave;                    // ks = i, nt-local = wave
        int gp = i * 8 + nb * 4 + wave;          // global (ks,nt) pair
        __builtin_amdgcn_global_load_lds(
            (const __attribute__((address_space(1))) void*)
                ((const char*)Wpk + (size_t)gp * 1024 + lane * 16),
            (__attribute__((address_space(3))) void*)
                ((char*)wlds + (size_t)c * 1024),
            16, 0, 0);
    }
    // stage A tile: 32 chunks of 1 KB; chunk c covers rows 2c,2c+1.
    // Per-lane PRE-SWIZZLED global source (scol = col16 ^ (row&7), stays
    // within its Xh/Ah half), linear LDS dest.
#pragma unroll
    for (int i = 0; i < 8; ++i) {
        int c = wave * 8 + i;
        int row = 2 * c + (lane >> 5);
        int col16 = lane & 31;                   // 16B unit within 512B row
        int scol = col16 ^ (row & 7);
        int m = rowbase + row;
        const _Float16* src = (scol < 16)
            ? Xh + (size_t)m * DIN + scol * 8
            : Ah + (size_t)m * DIN + (scol - 16) * 8;
        __builtin_amdgcn_global_load_lds(
            (const __attribute__((address_space(1))) void*)src,
            (__attribute__((address_space(3))) void*)
                ((char*)aLds + (size_t)c * 1024),
            16, 0, 0);
    }

    f32x4 acc[4];
#pragma unroll
    for (int mt = 0; mt < 4; ++mt) acc[mt] = (f32x4){0.f, 0.f, 0.f, 0.f};

    __syncthreads();   // drains all 16 DMA chunks/wave; only barrier

#pragma unroll
    for (int ks = 0; ks < 8; ++ks) {
        half8_t bfr = *(const half8_t*)(wlds + (size_t)(ks * 4 + wave) * 512 + lane * 8);
#pragma unroll
        for (int mt = 0; mt < 4; ++mt) {
            int row = mt * 16 + ln;
            int u = (ks * 4 + quad) ^ (row & 7);         // swizzled 16B unit
            half8_t af = *(const half8_t*)(
                (const char*)aLds + (size_t)row * 512 + (size_t)u * 16);
            acc[mt] = __builtin_amdgcn_mfma_f32_16x16x32_f16(af, bfr, acc[mt], 0, 0, 0);
        }
    }

    // epilogue: bias + S*w_edge, f16 Hh store, wave-exclusive channel stats
    const int c = nb * 64 + wave * 16 + ln;
    const float bs = bself[c];
    const float we = wedge[c];
    float psum = 0.0f, psq = 0.0f;

#pragma unroll
    for (int mt = 0; mt < 4; ++mt) {
        const int rb = rowbase + mt * 16 + quad * 4;
        float sv[4];
#pragma unroll
        for (int r = 0; r < 4; ++r) sv[r] = S[rb + r];
#pragma unroll
        for (int r = 0; r < 4; ++r) {
            float h = acc[mt][r] + bs + sv[r] * we;
            Hh[(size_t)(rb + r) * DOUT + c] = (_Float16)h;
            psum += h;
            psq += h * h;
        }
    }
    // reduce across the 4 quads (rows) -> lanes 0..15 hold channel totals
    psum += __shfl_down(psum, 32);
    psum += __shfl_down(psum, 16);
    psq  += __shfl_down(psq, 32);
    psq  += __shfl_down(psq, 16);
    if (lane < 16) {
        atomicAdd(&gsum[c], psum);
        atomicAdd(&gsumsq[c], psq);
    }
}

// ---------------------------------------------------------------------------
// 4) streaming normalize + ReLU: read f16 Hh (20.5 MB), write fp32 H (41 MB).
// ---------------------------------------------------------------------------
__global__ __launch_bounds__(256) void norm_relu_kernel(
    const _Float16* __restrict__ Hh, float* __restrict__ H,
    const float* __restrict__ gsum, const float* __restrict__ gsumsq,
    const float* __restrict__ gamma, const float* __restrict__ beta)
{
    const int total = M_ * DOUT / 8;           // 1.28M groups of 8 f16
    for (int idx = blockIdx.x * 256 + threadIdx.x; idx < total;
         idx += gridDim.x * 256) {
        int o8 = (idx & 15) * 8;               // channel base (0..120)
        float4 s0 = *(const float4*)(gsum + o8);
        float4 s1 = *(const float4*)(gsum + o8 + 4);
        float4 q0 = *(const float4*)(gsumsq + o8);
        float4 q1 = *(const float4*)(gsumsq + o8 + 4);
        float4 g0 = *(const float4*)(gamma + o8);
        float4 g1 = *(const float4*)(gamma + o8 + 4);
        float4 b0 = *(const float4*)(beta + o8);
        float4 b1 = *(const float4*)(beta + o8 + 4);
        float sc[8], sh[8];
        float svv[8] = {s0.x, s0.y, s0.z, s0.w, s1.x, s1.y, s1.z, s1.w};
        float qv[8] = {q0.x, q0.y, q0.z, q0.w, q1.x, q1.y, q1.z, q1.w};
        float gv[8] = {g0.x, g0.y, g0.z, g0.w, g1.x, g1.y, g1.z, g1.w};
        float bv[8] = {b0.x, b0.y, b0.z, b0.w, b1.x, b1.y, b1.z, b1.w};
#pragma unroll
        for (int j = 0; j < 8; ++j) {
            float mean = svv[j] * NINV;
            float rstd = rsqrtf(qv[j] * NINV - mean * mean + BN_EPS);
            sc[j] = gv[j] * rstd;
            sh[j] = bv[j] - mean * sc[j];
        }
        half8_t hv = ((const half8_t*)Hh)[idx];
        float4 o0, o1;
        o0.x = fmaxf((float)hv[0] * sc[0] + sh[0], 0.0f);
        o0.y = fmaxf((float)hv[1] * sc[1] + sh[1], 0.0f);
        o0.z = fmaxf((float)hv[2] * sc[2] + sh[2], 0.0f);
        o0.w = fmaxf((float)hv[3] * sc[3] + sh[3], 0.0f);
        o1.x = fmaxf((float)hv[4] * sc[4] + sh[4], 0.0f);
        o1.y = fmaxf((float)hv[5] * sc[5] + sh[5], 0.0f);
        o1.z = fmaxf((float)hv[6] * sc[6] + sh[6], 0.0f);
        o1.w = fmaxf((float)hv[7] * sc[7] + sh[7], 0.0f);
        ((float4*)H)[idx * 2]     = o0;
        ((float4*)H)[idx * 2 + 1] = o1;
    }
}

// ---------------------------------------------------------------------------
extern "C" void kernel_launch(void* const* d_in, const int* in_sizes, int n_in,
                              void* d_out, int out_size, void* d_ws, size_t ws_size,
                              hipStream_t stream)
{
    const float* X      = (const float*)d_in[0];
    const float* EA     = (const float*)d_in[1];
    const float* Wnode  = (const float*)d_in[2];
    const float* Wedge  = (const float*)d_in[3];
    const float* Wself  = (const float*)d_in[4];
    const float* bself  = (const float*)d_in[5];
    const float* gamma  = (const float*)d_in[6];
    const float* beta   = (const float*)d_in[7];
    const int*   EI     = (const int*)d_in[8];

    int*   wsI    = (int*)d_ws;
    float* wsF    = (float*)d_ws;
    int*   cnt    = wsI + WS_CNT;
    float* gsum   = wsF + WS_SUM;
    float* gsumsq = wsF + WS_SUMSQ;
    float* S      = wsF + WS_S;
    int*   ssrc   = wsI + WS_SSRC;
    float* EAs    = wsF + WS_EAS;
    _Float16* Hh  = (_Float16*)(wsI + WS_HH);   // aliases EAs (dead after gather)
    _Float16* Wpk = (_Float16*)(wsI + WS_WPK);
    _Float16* Xh  = (_Float16*)(wsI + WS_XH);
    _Float16* Ah  = (_Float16*)(wsI + WS_AH);
    float* H      = (float*)d_out;

    // zero cnt + gsum + gsumsq (41 KB)
    hipMemsetAsync(d_ws, 0, (size_t)WS_ZERO_UNITS * 4, stream);

    // fused prep: xcvt (10000 blocks) + W pack (16) + edge scatter (625)
    prep_kernel<<<10641, 256, 0, stream>>>(X, Xh, Wself, Wnode, Wpk, EI, EA,
                                           cnt, ssrc, EAs);

    // gather-reduce -> Ah, S  (batch-per-XCD swizzle, 4 edges/load-step)
    gather_kernel<<<M_ / 4, 256, 0, stream>>>(Xh, EAs, cnt, ssrc, Ah, S);

    // dual-DMA-staged GEMM -> f16 Hh + gsum/gsumsq via atomics
    gemm_stats_kernel<<<GEMM_BLOCKS, 256, 0, stream>>>(Xh, Ah, Wpk, S, bself,
                                                       Wedge, Hh, gsum, gsumsq);

    // streaming normalize + ReLU: f16 in, fp32 out
    norm_relu_kernel<<<2048, 256, 0, stream>>>(Hh, H, gsum, gsumsq, gamma, beta);
}